// Round 5
// baseline (339.927 us; speedup 1.0000x reference)
//
#include <hip/hip_runtime.h>

#define D 128

// ---------- K1: fold W_attn through W_rel: g1[128], g2[128], c ----------
__global__ __launch_bounds__(256) void precompute_g(
    const float* __restrict__ Wrel,   // [128][256]
    const float* __restrict__ brel,   // [128]
    const float* __restrict__ Wattn,  // [256]
    float* __restrict__ gbuf)         // [257]: g1|g2|c
{
    int k = threadIdx.x;  // 0..255
    float acc = 0.f;
    for (int j = 0; j < 128; ++j)
        acc += Wattn[128 + j] * Wrel[j * 256 + k];
    gbuf[k] = acc;
    if (k == 0) {
        float c = 0.f;
        for (int j = 0; j < 128; ++j) c += Wattn[128 + j] * brel[j];
        gbuf[256] = c;
    }
}

// ---------- K2: z = x @ W_fc^T, fused p = attn1.z, q = g2.z ----------
// x-tile in LDS (34 KB -> 4 blocks/CU); W direct from L2 (64 KB, hot,
// broadcast across the 16 ty-lanes sharing each address).
__global__ __launch_bounds__(256) void zgemm_pq(
    const float* __restrict__ x, const float* __restrict__ W,
    const float* __restrict__ attn, const float* __restrict__ gbuf,
    float* __restrict__ z, float* __restrict__ pbuf, float* __restrict__ qbuf,
    int nrows)
{
    __shared__ float xs[64][132];
    int tid = threadIdx.x;
    int row0 = blockIdx.x * 64;

    for (int i = tid; i < 64 * 32; i += 256) {
        int r = i >> 5, k4 = (i & 31) << 2;
        int gr = row0 + r;
        float4 v = make_float4(0.f, 0.f, 0.f, 0.f);
        if (gr < nrows) v = *(const float4*)&x[(size_t)gr * D + k4];
        *(float4*)&xs[r][k4] = v;
    }
    __syncthreads();

    int tx = tid & 15, ty = tid >> 4;   // rows ty*4+i, cols tx+16*j
    float acc[4][8] = {};
    for (int k = 0; k < 128; k += 4) {
        float4 xv[4], wv[8];
#pragma unroll
        for (int j = 0; j < 8; ++j)
            wv[j] = *(const float4*)&W[(size_t)(tx + 16 * j) * D + k];
#pragma unroll
        for (int i = 0; i < 4; ++i)
            xv[i] = *(const float4*)&xs[ty * 4 + i][k];
#pragma unroll
        for (int i = 0; i < 4; ++i)
#pragma unroll
            for (int j = 0; j < 8; ++j)
                acc[i][j] += xv[i].x * wv[j].x + xv[i].y * wv[j].y +
                             xv[i].z * wv[j].z + xv[i].w * wv[j].w;
    }

    // epilogue: write z, reduce p/q across the 16 tx lanes of each row
    float a1[8], g2[8];
#pragma unroll
    for (int j = 0; j < 8; ++j) {
        a1[j] = attn[tx + 16 * j];
        g2[j] = gbuf[128 + tx + 16 * j];
    }
#pragma unroll
    for (int i = 0; i < 4; ++i) {
        int gr = row0 + ty * 4 + i;
        if (gr >= nrows) continue;
        float ps = 0.f, qs = 0.f;
#pragma unroll
        for (int j = 0; j < 8; ++j) {
            z[(size_t)gr * D + tx + 16 * j] = acc[i][j];
            ps += a1[j] * acc[i][j];
            qs += g2[j] * acc[i][j];
        }
#pragma unroll
        for (int off = 8; off >= 1; off >>= 1) {
            ps += __shfl_xor(ps, off);
            qs += __shfl_xor(qs, off);
        }
        if (tx == 0) { pbuf[gr] = ps; qbuf[gr] = qs; }
    }
}

// ---------- K3: per-edge ex = exp(leaky_relu(logit)) + fused degree count --
// Segment-max subtraction skipped: logits bounded far below exp overflow for
// this model's scales; alpha = ex/denom identical up to rounding.
__global__ __launch_bounds__(256) void edge_logits(
    const float* __restrict__ ef,
    const int* __restrict__ src, const int* __restrict__ dst,
    const float* __restrict__ gbuf,   // g1|g2|c
    const float* __restrict__ pbuf, const float* __restrict__ qbuf,
    float* __restrict__ ebuf, int* __restrict__ cnt, int E)
{
    int tid = threadIdx.x;
    int lane = tid & 15;
    int e = blockIdx.x * 16 + (tid >> 4);
    if (e >= E) return;
    const float* efr = ef + (size_t)e * D;
    float acc = 0.f;
#pragma unroll
    for (int p = 0; p < 2; ++p) {
        int idx = lane * 4 + p * 64;
        float4 a4  = *(const float4*)&efr[idx];
        float4 g14 = *(const float4*)&gbuf[idx];
        acc += a4.x * g14.x + a4.y * g14.y + a4.z * g14.z + a4.w * g14.w;
    }
#pragma unroll
    for (int off = 8; off >= 1; off >>= 1) acc += __shfl_xor(acc, off);
    if (lane == 0) {
        int d = dst[e];
        float a = acc + pbuf[src[e]] + qbuf[d] + gbuf[256];
        float ev = a > 0.f ? a : 0.01f * a;
        ebuf[e] = __expf(ev);
        atomicAdd(&cnt[d], 1);
    }
}

// ---------- K4a: per-1024-chunk sums ----------
__global__ __launch_bounds__(256) void partial_sums(
    const int* __restrict__ cnt, int* __restrict__ bsum, int N)
{
    __shared__ int ws_[4];
    int tid = threadIdx.x, lane = tid & 63, wid = tid >> 6;
    int i0 = blockIdx.x * 1024 + tid * 4;
    int s = 0;
#pragma unroll
    for (int j = 0; j < 4; ++j) s += (i0 + j < N) ? cnt[i0 + j] : 0;
#pragma unroll
    for (int off = 32; off >= 1; off >>= 1) s += __shfl_xor(s, off);
    if (lane == 0) ws_[wid] = s;
    __syncthreads();
    if (tid == 0) bsum[blockIdx.x] = ws_[0] + ws_[1] + ws_[2] + ws_[3];
}

// ---------- K4b: single-block exclusive scan of chunk sums (nb<=256) -------
__global__ __launch_bounds__(256) void scan_partials(
    const int* __restrict__ bsum, int* __restrict__ boffs, int nb)
{
    __shared__ int ws_[4];
    int tid = threadIdx.x, lane = tid & 63, wid = tid >> 6;
    int v = (tid < nb) ? bsum[tid] : 0;
    int incl = v;
#pragma unroll
    for (int off = 1; off < 64; off <<= 1) {
        int t = __shfl_up(incl, off);
        if (lane >= off) incl += t;
    }
    if (lane == 63) ws_[wid] = incl;
    __syncthreads();
    int woff = 0;
    for (int w = 0; w < wid; ++w) woff += ws_[w];
    if (tid < nb) boffs[tid] = woff + incl - v;
}

// ---------- K4c: per-chunk local scan -> offs, cursor(=offs copy) ----------
__global__ __launch_bounds__(256) void local_scan(
    const int* __restrict__ cnt, const int* __restrict__ boffs,
    int* __restrict__ offs, int* __restrict__ cursor, int N, int E)
{
    __shared__ int ws_[4];
    int tid = threadIdx.x, lane = tid & 63, wid = tid >> 6;
    int i0 = blockIdx.x * 1024 + tid * 4;
    int v[4];
    int tsum = 0;
#pragma unroll
    for (int j = 0; j < 4; ++j) {
        v[j] = (i0 + j < N) ? cnt[i0 + j] : 0;
        tsum += v[j];
    }
    int incl = tsum;
#pragma unroll
    for (int off = 1; off < 64; off <<= 1) {
        int t = __shfl_up(incl, off);
        if (lane >= off) incl += t;
    }
    if (lane == 63) ws_[wid] = incl;
    __syncthreads();
    int woff = 0;
    for (int w = 0; w < wid; ++w) woff += ws_[w];
    int run = boffs[blockIdx.x] + woff + incl - tsum;
#pragma unroll
    for (int j = 0; j < 4; ++j) {
        if (i0 + j < N) { offs[i0 + j] = run; cursor[i0 + j] = run; }
        run += v[j];
    }
    if (blockIdx.x == 0 && tid == 0) offs[N] = E;
}

// ---------- K5: scatter packed (src, ex) into absolute CSR slots ----------
__global__ __launch_bounds__(256) void scatter_csr(
    const int* __restrict__ src, const int* __restrict__ dst,
    const float* __restrict__ ebuf, int* __restrict__ cursor,
    int2* __restrict__ spack, int E)
{
    int e = blockIdx.x * 256 + threadIdx.x;
    if (e >= E) return;
    int pos = atomicAdd(&cursor[dst[e]], 1);
    spack[pos] = make_int2(src[e], __float_as_int(ebuf[e]));
}

// ---------- K6: per-node gather: softmax-weighted sum of z[src] ----------
__global__ __launch_bounds__(256) void node_gather(
    const float* __restrict__ z, const int2* __restrict__ spack,
    const int* __restrict__ offs, float* __restrict__ out, int N)
{
    int tid = threadIdx.x, lane = tid & 63;
    int node = blockIdx.x * 4 + (tid >> 6);
    if (node >= N) return;
    int o0 = offs[node], o1 = offs[node + 1];
    float2 acc = make_float2(0.f, 0.f);
    float denom = 0.f;
    int j = o0;
    for (; j + 3 < o1; j += 4) {
        int2 p0 = spack[j], p1 = spack[j + 1], p2 = spack[j + 2], p3 = spack[j + 3];
        float2 v0 = *(const float2*)&z[(size_t)p0.x * D + lane * 2];
        float2 v1 = *(const float2*)&z[(size_t)p1.x * D + lane * 2];
        float2 v2 = *(const float2*)&z[(size_t)p2.x * D + lane * 2];
        float2 v3 = *(const float2*)&z[(size_t)p3.x * D + lane * 2];
        float x0 = __int_as_float(p0.y), x1 = __int_as_float(p1.y);
        float x2 = __int_as_float(p2.y), x3 = __int_as_float(p3.y);
        denom += (x0 + x1) + (x2 + x3);
        acc.x += x0 * v0.x + x1 * v1.x + x2 * v2.x + x3 * v3.x;
        acc.y += x0 * v0.y + x1 * v1.y + x2 * v2.y + x3 * v3.y;
    }
    for (; j < o1; ++j) {
        int2 p0 = spack[j];
        float x0 = __int_as_float(p0.y);
        float2 v0 = *(const float2*)&z[(size_t)p0.x * D + lane * 2];
        denom += x0;
        acc.x += x0 * v0.x;
        acc.y += x0 * v0.y;
    }
    if (o1 > o0) {
        float inv = 1.f / denom;
        acc.x *= inv;
        acc.y *= inv;
    }
    *(float2*)&out[(size_t)node * D + lane * 2] = acc;
}

extern "C" void kernel_launch(void* const* d_in, const int* in_sizes, int n_in,
                              void* d_out, int out_size, void* d_ws, size_t ws_size,
                              hipStream_t stream) {
    const float* x     = (const float*)d_in[0];
    const float* ef    = (const float*)d_in[1];
    const int*   src   = (const int*)d_in[2];
    const int*   dst   = (const int*)d_in[3];
    const float* Wfc   = (const float*)d_in[4];
    const float* Wrel  = (const float*)d_in[5];
    const float* brel  = (const float*)d_in[6];
    const float* Wattn = (const float*)d_in[7];
    int N = in_sizes[0] / D;
    int E = in_sizes[2];
    int nb = (N + 1023) / 1024;
    float* out = (float*)d_out;

    // workspace layout (4B units; spack first after z for 8B alignment)
    float* z      = (float*)d_ws;                 // N*D
    int2*  spack  = (int2*)(z + (size_t)N * D);   // E
    float* ebuf   = (float*)(spack + E);          // E
    float* pbuf   = ebuf + E;                     // N
    float* qbuf   = pbuf + N;                     // N
    int*   cnt    = (int*)(qbuf + N);             // N
    int*   cursor = cnt + N;                      // N
    int*   offs   = cursor + N;                   // N+16 (padded)
    int*   bsum   = offs + N + 16;                // 256
    int*   boffs  = bsum + 256;                   // 256
    float* gbuf   = (float*)(boffs + 256);        // 257

    hipMemsetAsync(cnt, 0, (size_t)N * sizeof(int), stream);

    precompute_g<<<1, 256, 0, stream>>>(Wrel, brel, Wattn, gbuf);
    zgemm_pq<<<(N + 63) / 64, 256, 0, stream>>>(x, Wfc, Wattn, gbuf, z, pbuf,
                                                qbuf, N);
    edge_logits<<<(E + 15) / 16, 256, 0, stream>>>(ef, src, dst, gbuf, pbuf,
                                                   qbuf, ebuf, cnt, E);
    partial_sums<<<nb, 256, 0, stream>>>(cnt, bsum, N);
    scan_partials<<<1, 256, 0, stream>>>(bsum, boffs, nb);
    local_scan<<<nb, 256, 0, stream>>>(cnt, boffs, offs, cursor, N, E);
    scatter_csr<<<(E + 255) / 256, 256, 0, stream>>>(src, dst, ebuf, cursor,
                                                     spack, E);
    node_gather<<<(N + 3) / 4, 256, 0, stream>>>(z, spack, offs, out, N);
}

// Round 6
// 288.199 us; speedup vs baseline: 1.1795x; 1.1795x over previous
//
#include <hip/hip_runtime.h>

#define D 128

__device__ __forceinline__ unsigned short f2bf(float f) {
    unsigned u = __float_as_uint(f);
    u += 0x7fffu + ((u >> 16) & 1u);   // round-to-nearest-even
    return (unsigned short)(u >> 16);
}

// ---------- K1: fold W_attn through W_rel: g1[128], g2[128], c ----------
__global__ __launch_bounds__(256) void precompute_g(
    const float* __restrict__ Wrel,   // [128][256]
    const float* __restrict__ brel,   // [128]
    const float* __restrict__ Wattn,  // [256]
    float* __restrict__ gbuf)         // [257]: g1|g2|c
{
    int k = threadIdx.x;  // 0..255
    float acc = 0.f;
    for (int j = 0; j < 128; ++j)
        acc += Wattn[128 + j] * Wrel[j * 256 + k];
    gbuf[k] = acc;
    if (k == 0) {
        float c = 0.f;
        for (int j = 0; j < 128; ++j) c += Wattn[128 + j] * brel[j];
        gbuf[256] = c;
    }
}

// ---------- K2: z = x @ W_fc^T (R3 LDS structure, float4 reads),
//             fused p = attn1.z, q = g2.z (exact fp32), z stored bf16 -------
__global__ __launch_bounds__(256) void zgemm_pq(
    const float* __restrict__ x, const float* __restrict__ W,
    const float* __restrict__ attn, const float* __restrict__ gbuf,
    unsigned short* __restrict__ zb, float* __restrict__ pbuf,
    float* __restrict__ qbuf, int nrows)
{
    __shared__ float xs[64][132];
    __shared__ float ws[128][132];
    int tid = threadIdx.x;
    int row0 = blockIdx.x * 64;

    for (int i = tid; i < 128 * 32; i += 256) {
        int c = i >> 5, k4 = (i & 31) << 2;
        float4 v = *(const float4*)&W[c * 128 + k4];
        *(float4*)&ws[c][k4] = v;
    }
    for (int i = tid; i < 64 * 32; i += 256) {
        int r = i >> 5, k4 = (i & 31) << 2;
        int gr = row0 + r;
        float4 v = make_float4(0.f, 0.f, 0.f, 0.f);
        if (gr < nrows) v = *(const float4*)&x[(size_t)gr * D + k4];
        *(float4*)&xs[r][k4] = v;
    }
    __syncthreads();

    int tx = tid & 15, ty = tid >> 4;   // rows ty*4+i, cols tx+16*j
    float acc[4][8] = {};
    for (int k = 0; k < 128; k += 4) {
        float4 xv[4], wv[8];
#pragma unroll
        for (int i = 0; i < 4; ++i) xv[i] = *(const float4*)&xs[ty * 4 + i][k];
#pragma unroll
        for (int j = 0; j < 8; ++j) wv[j] = *(const float4*)&ws[tx + 16 * j][k];
#pragma unroll
        for (int i = 0; i < 4; ++i)
#pragma unroll
            for (int j = 0; j < 8; ++j)
                acc[i][j] += xv[i].x * wv[j].x + xv[i].y * wv[j].y +
                             xv[i].z * wv[j].z + xv[i].w * wv[j].w;
    }

    // epilogue: bf16 z write + exact fp32 p/q reduced over the 16 tx lanes
    float a1[8], g2[8];
#pragma unroll
    for (int j = 0; j < 8; ++j) {
        a1[j] = attn[tx + 16 * j];
        g2[j] = gbuf[128 + tx + 16 * j];
    }
#pragma unroll
    for (int i = 0; i < 4; ++i) {
        int gr = row0 + ty * 4 + i;
        if (gr >= nrows) continue;
        float ps = 0.f, qs = 0.f;
#pragma unroll
        for (int j = 0; j < 8; ++j) {
            zb[(size_t)gr * D + tx + 16 * j] = f2bf(acc[i][j]);
            ps += a1[j] * acc[i][j];
            qs += g2[j] * acc[i][j];
        }
#pragma unroll
        for (int off = 8; off >= 1; off >>= 1) {
            ps += __shfl_xor(ps, off);
            qs += __shfl_xor(qs, off);
        }
        if (tx == 0) { pbuf[gr] = ps; qbuf[gr] = qs; }
    }
}

// ---------- K3: per-edge ex = exp(leaky_relu(logit)) + fused degree count --
// Segment-max subtraction skipped: logits bounded far below exp overflow for
// this model's scales; alpha = ex/denom identical up to rounding.
__global__ __launch_bounds__(256) void edge_logits(
    const float* __restrict__ ef,
    const int* __restrict__ src, const int* __restrict__ dst,
    const float* __restrict__ gbuf,   // g1|g2|c
    const float* __restrict__ pbuf, const float* __restrict__ qbuf,
    float* __restrict__ ebuf, int* __restrict__ cnt, int E)
{
    int tid = threadIdx.x;
    int lane = tid & 15;
    int e = blockIdx.x * 16 + (tid >> 4);
    if (e >= E) return;
    const float* efr = ef + (size_t)e * D;
    float acc = 0.f;
#pragma unroll
    for (int p = 0; p < 2; ++p) {
        int idx = lane * 4 + p * 64;
        float4 a4  = *(const float4*)&efr[idx];
        float4 g14 = *(const float4*)&gbuf[idx];
        acc += a4.x * g14.x + a4.y * g14.y + a4.z * g14.z + a4.w * g14.w;
    }
#pragma unroll
    for (int off = 8; off >= 1; off >>= 1) acc += __shfl_xor(acc, off);
    if (lane == 0) {
        int d = dst[e];
        float a = acc + pbuf[src[e]] + qbuf[d] + gbuf[256];
        float ev = a > 0.f ? a : 0.01f * a;
        ebuf[e] = __expf(ev);
        atomicAdd(&cnt[d], 1);
    }
}

// ---------- K4a: per-1024-chunk sums ----------
__global__ __launch_bounds__(256) void partial_sums(
    const int* __restrict__ cnt, int* __restrict__ bsum, int N)
{
    __shared__ int ws_[4];
    int tid = threadIdx.x, lane = tid & 63, wid = tid >> 6;
    int i0 = blockIdx.x * 1024 + tid * 4;
    int s = 0;
#pragma unroll
    for (int j = 0; j < 4; ++j) s += (i0 + j < N) ? cnt[i0 + j] : 0;
#pragma unroll
    for (int off = 32; off >= 1; off >>= 1) s += __shfl_xor(s, off);
    if (lane == 0) ws_[wid] = s;
    __syncthreads();
    if (tid == 0) bsum[blockIdx.x] = ws_[0] + ws_[1] + ws_[2] + ws_[3];
}

// ---------- K4b: single-block exclusive scan of chunk sums (nb<=256) -------
__global__ __launch_bounds__(256) void scan_partials(
    const int* __restrict__ bsum, int* __restrict__ boffs, int nb)
{
    __shared__ int ws_[4];
    int tid = threadIdx.x, lane = tid & 63, wid = tid >> 6;
    int v = (tid < nb) ? bsum[tid] : 0;
    int incl = v;
#pragma unroll
    for (int off = 1; off < 64; off <<= 1) {
        int t = __shfl_up(incl, off);
        if (lane >= off) incl += t;
    }
    if (lane == 63) ws_[wid] = incl;
    __syncthreads();
    int woff = 0;
    for (int w = 0; w < wid; ++w) woff += ws_[w];
    if (tid < nb) boffs[tid] = woff + incl - v;
}

// ---------- K4c: per-chunk local scan -> offs, cursor(=offs copy) ----------
__global__ __launch_bounds__(256) void local_scan(
    const int* __restrict__ cnt, const int* __restrict__ boffs,
    int* __restrict__ offs, int* __restrict__ cursor, int N, int E)
{
    __shared__ int ws_[4];
    int tid = threadIdx.x, lane = tid & 63, wid = tid >> 6;
    int i0 = blockIdx.x * 1024 + tid * 4;
    int v[4];
    int tsum = 0;
#pragma unroll
    for (int j = 0; j < 4; ++j) {
        v[j] = (i0 + j < N) ? cnt[i0 + j] : 0;
        tsum += v[j];
    }
    int incl = tsum;
#pragma unroll
    for (int off = 1; off < 64; off <<= 1) {
        int t = __shfl_up(incl, off);
        if (lane >= off) incl += t;
    }
    if (lane == 63) ws_[wid] = incl;
    __syncthreads();
    int woff = 0;
    for (int w = 0; w < wid; ++w) woff += ws_[w];
    int run = boffs[blockIdx.x] + woff + incl - tsum;
#pragma unroll
    for (int j = 0; j < 4; ++j) {
        if (i0 + j < N) { offs[i0 + j] = run; cursor[i0 + j] = run; }
        run += v[j];
    }
    if (blockIdx.x == 0 && tid == 0) offs[N] = E;
}

// ---------- K5: scatter packed (src, ex) into absolute CSR slots ----------
__global__ __launch_bounds__(256) void scatter_csr(
    const int* __restrict__ src, const int* __restrict__ dst,
    const float* __restrict__ ebuf, int* __restrict__ cursor,
    int2* __restrict__ spack, int E)
{
    int e = blockIdx.x * 256 + threadIdx.x;
    if (e >= E) return;
    int pos = atomicAdd(&cursor[dst[e]], 1);
    spack[pos] = make_int2(src[e], __float_as_int(ebuf[e]));
}

// ---------- K6: per-node gather: softmax-weighted sum of bf16 z[src] -------
__global__ __launch_bounds__(256) void node_gather(
    const unsigned short* __restrict__ zb, const int2* __restrict__ spack,
    const int* __restrict__ offs, float* __restrict__ out, int N)
{
    int tid = threadIdx.x, lane = tid & 63;
    int node = blockIdx.x * 4 + (tid >> 6);
    if (node >= N) return;
    int o0 = offs[node], o1 = offs[node + 1];
    float2 acc = make_float2(0.f, 0.f);
    float denom = 0.f;
    int j = o0;
    for (; j + 1 < o1; j += 2) {
        int2 p0 = spack[j], p1 = spack[j + 1];
        unsigned u0 = *(const unsigned*)&zb[(size_t)p0.x * D + lane * 2];
        unsigned u1 = *(const unsigned*)&zb[(size_t)p1.x * D + lane * 2];
        float x0 = __int_as_float(p0.y), x1 = __int_as_float(p1.y);
        denom += x0 + x1;
        acc.x += x0 * __uint_as_float(u0 << 16) +
                 x1 * __uint_as_float(u1 << 16);
        acc.y += x0 * __uint_as_float(u0 & 0xffff0000u) +
                 x1 * __uint_as_float(u1 & 0xffff0000u);
    }
    if (j < o1) {
        int2 p0 = spack[j];
        unsigned u0 = *(const unsigned*)&zb[(size_t)p0.x * D + lane * 2];
        float x0 = __int_as_float(p0.y);
        denom += x0;
        acc.x += x0 * __uint_as_float(u0 << 16);
        acc.y += x0 * __uint_as_float(u0 & 0xffff0000u);
    }
    if (o1 > o0) {
        float inv = 1.f / denom;
        acc.x *= inv;
        acc.y *= inv;
    }
    *(float2*)&out[(size_t)node * D + lane * 2] = acc;
}

extern "C" void kernel_launch(void* const* d_in, const int* in_sizes, int n_in,
                              void* d_out, int out_size, void* d_ws, size_t ws_size,
                              hipStream_t stream) {
    const float* x     = (const float*)d_in[0];
    const float* ef    = (const float*)d_in[1];
    const int*   src   = (const int*)d_in[2];
    const int*   dst   = (const int*)d_in[3];
    const float* Wfc   = (const float*)d_in[4];
    const float* Wrel  = (const float*)d_in[5];
    const float* brel  = (const float*)d_in[6];
    const float* Wattn = (const float*)d_in[7];
    int N = in_sizes[0] / D;
    int E = in_sizes[2];
    int nb = (N + 1023) / 1024;
    float* out = (float*)d_out;

    // workspace layout (zb bf16 first; spack 8B-aligned; gbuf 16B-aligned)
    unsigned short* zb = (unsigned short*)d_ws;          // N*D bf16
    int2*  spack  = (int2*)(zb + (size_t)N * D);         // E
    float* ebuf   = (float*)(spack + E);                 // E
    float* pbuf   = ebuf + E;                            // N
    float* qbuf   = pbuf + N;                            // N
    int*   cnt    = (int*)(qbuf + N);                    // N
    int*   cursor = cnt + N;                             // N
    int*   offs   = cursor + N;                          // N+16 (padded)
    int*   bsum   = offs + N + 16;                       // 256
    int*   boffs  = bsum + 256;                          // 256
    float* gbuf   = (float*)(boffs + 256);               // 257

    hipMemsetAsync(cnt, 0, (size_t)N * sizeof(int), stream);

    precompute_g<<<1, 256, 0, stream>>>(Wrel, brel, Wattn, gbuf);
    zgemm_pq<<<(N + 63) / 64, 256, 0, stream>>>(x, Wfc, Wattn, gbuf, zb, pbuf,
                                                qbuf, N);
    edge_logits<<<(E + 15) / 16, 256, 0, stream>>>(ef, src, dst, gbuf, pbuf,
                                                   qbuf, ebuf, cnt, E);
    partial_sums<<<nb, 256, 0, stream>>>(cnt, bsum, N);
    scan_partials<<<1, 256, 0, stream>>>(bsum, boffs, nb);
    local_scan<<<nb, 256, 0, stream>>>(cnt, boffs, offs, cursor, N, E);
    scatter_csr<<<(E + 255) / 256, 256, 0, stream>>>(src, dst, ebuf, cursor,
                                                     spack, E);
    node_gather<<<(N + 3) / 4, 256, 0, stream>>>(zb, spack, offs, out, N);
}

// Round 7
// 257.384 us; speedup vs baseline: 1.3207x; 1.1197x over previous
//
#include <hip/hip_runtime.h>

#define D 128

__device__ __forceinline__ unsigned short f2bf(float f) {
    unsigned u = __float_as_uint(f);
    u += 0x7fffu + ((u >> 16) & 1u);   // round-to-nearest-even
    return (unsigned short)(u >> 16);
}
__device__ __forceinline__ float bf_lo(unsigned u) { return __uint_as_float(u << 16); }
__device__ __forceinline__ float bf_hi(unsigned u) { return __uint_as_float(u & 0xffff0000u); }

// ---------- K1: block0 folds W_attn through W_rel -> g1|g2|c;
//             blocks 1.. count dst degrees ----------
__global__ __launch_bounds__(256) void g_and_count(
    const float* __restrict__ Wrel,   // [128][256]
    const float* __restrict__ brel,   // [128]
    const float* __restrict__ Wattn,  // [256]
    const int* __restrict__ dst,
    float* __restrict__ gbuf,         // [257]: g1|g2|c
    int* __restrict__ cnt, int E)
{
    if (blockIdx.x == 0) {
        int k = threadIdx.x;  // 0..255
        float acc = 0.f;
        for (int j = 0; j < 128; ++j)
            acc += Wattn[128 + j] * Wrel[j * 256 + k];
        gbuf[k] = acc;
        if (k == 0) {
            float c = 0.f;
            for (int j = 0; j < 128; ++j) c += Wattn[128 + j] * brel[j];
            gbuf[256] = c;
        }
    } else {
        int e = (blockIdx.x - 1) * 256 + threadIdx.x;
        if (e < E) atomicAdd(&cnt[dst[e]], 1);
    }
}

// ---------- K2: z = x @ W_fc^T (double-LDS, float4 reads),
//             fused p = attn1.z, q = g2.z (exact fp32), z stored bf16 -------
__global__ __launch_bounds__(256) void zgemm_pq(
    const float* __restrict__ x, const float* __restrict__ W,
    const float* __restrict__ attn, const float* __restrict__ gbuf,
    unsigned short* __restrict__ zb, float* __restrict__ pbuf,
    float* __restrict__ qbuf, int nrows)
{
    __shared__ float xs[64][132];
    __shared__ float ws[128][132];
    int tid = threadIdx.x;
    int row0 = blockIdx.x * 64;

    for (int i = tid; i < 128 * 32; i += 256) {
        int c = i >> 5, k4 = (i & 31) << 2;
        float4 v = *(const float4*)&W[c * 128 + k4];
        *(float4*)&ws[c][k4] = v;
    }
    for (int i = tid; i < 64 * 32; i += 256) {
        int r = i >> 5, k4 = (i & 31) << 2;
        int gr = row0 + r;
        float4 v = make_float4(0.f, 0.f, 0.f, 0.f);
        if (gr < nrows) v = *(const float4*)&x[(size_t)gr * D + k4];
        *(float4*)&xs[r][k4] = v;
    }
    __syncthreads();

    int tx = tid & 15, ty = tid >> 4;   // rows ty*4+i, cols tx+16*j
    float acc[4][8] = {};
    for (int k = 0; k < 128; k += 4) {
        float4 xv[4], wv[8];
#pragma unroll
        for (int i = 0; i < 4; ++i) xv[i] = *(const float4*)&xs[ty * 4 + i][k];
#pragma unroll
        for (int j = 0; j < 8; ++j) wv[j] = *(const float4*)&ws[tx + 16 * j][k];
#pragma unroll
        for (int i = 0; i < 4; ++i)
#pragma unroll
            for (int j = 0; j < 8; ++j)
                acc[i][j] += xv[i].x * wv[j].x + xv[i].y * wv[j].y +
                             xv[i].z * wv[j].z + xv[i].w * wv[j].w;
    }

    // epilogue: bf16 z write + exact fp32 p/q reduced over the 16 tx lanes
    float a1[8], g2[8];
#pragma unroll
    for (int j = 0; j < 8; ++j) {
        a1[j] = attn[tx + 16 * j];
        g2[j] = gbuf[128 + tx + 16 * j];
    }
#pragma unroll
    for (int i = 0; i < 4; ++i) {
        int gr = row0 + ty * 4 + i;
        if (gr >= nrows) continue;
        float ps = 0.f, qs = 0.f;
#pragma unroll
        for (int j = 0; j < 8; ++j) {
            zb[(size_t)gr * D + tx + 16 * j] = f2bf(acc[i][j]);
            ps += a1[j] * acc[i][j];
            qs += g2[j] * acc[i][j];
        }
#pragma unroll
        for (int off = 8; off >= 1; off >>= 1) {
            ps += __shfl_xor(ps, off);
            qs += __shfl_xor(qs, off);
        }
        if (tx == 0) { pbuf[gr] = ps; qbuf[gr] = qs; }
    }
}

// ---------- K3a: per-1024-chunk sums ----------
__global__ __launch_bounds__(256) void partial_sums(
    const int* __restrict__ cnt, int* __restrict__ bsum, int N)
{
    __shared__ int ws_[4];
    int tid = threadIdx.x, lane = tid & 63, wid = tid >> 6;
    int i0 = blockIdx.x * 1024 + tid * 4;
    int s = 0;
#pragma unroll
    for (int j = 0; j < 4; ++j) s += (i0 + j < N) ? cnt[i0 + j] : 0;
#pragma unroll
    for (int off = 32; off >= 1; off >>= 1) s += __shfl_xor(s, off);
    if (lane == 0) ws_[wid] = s;
    __syncthreads();
    if (tid == 0) bsum[blockIdx.x] = ws_[0] + ws_[1] + ws_[2] + ws_[3];
}

// ---------- K3b: single-block exclusive scan of chunk sums (nb<=256) -------
__global__ __launch_bounds__(256) void scan_partials(
    const int* __restrict__ bsum, int* __restrict__ boffs, int nb)
{
    __shared__ int ws_[4];
    int tid = threadIdx.x, lane = tid & 63, wid = tid >> 6;
    int v = (tid < nb) ? bsum[tid] : 0;
    int incl = v;
#pragma unroll
    for (int off = 1; off < 64; off <<= 1) {
        int t = __shfl_up(incl, off);
        if (lane >= off) incl += t;
    }
    if (lane == 63) ws_[wid] = incl;
    __syncthreads();
    int woff = 0;
    for (int w = 0; w < wid; ++w) woff += ws_[w];
    if (tid < nb) boffs[tid] = woff + incl - v;
}

// ---------- K3c: per-chunk local scan -> offs, cursor(=offs copy) ----------
__global__ __launch_bounds__(256) void local_scan(
    const int* __restrict__ cnt, const int* __restrict__ boffs,
    int* __restrict__ offs, int* __restrict__ cursor, int N, int E)
{
    __shared__ int ws_[4];
    int tid = threadIdx.x, lane = tid & 63, wid = tid >> 6;
    int i0 = blockIdx.x * 1024 + tid * 4;
    int v[4];
    int tsum = 0;
#pragma unroll
    for (int j = 0; j < 4; ++j) {
        v[j] = (i0 + j < N) ? cnt[i0 + j] : 0;
        tsum += v[j];
    }
    int incl = tsum;
#pragma unroll
    for (int off = 1; off < 64; off <<= 1) {
        int t = __shfl_up(incl, off);
        if (lane >= off) incl += t;
    }
    if (lane == 63) ws_[wid] = incl;
    __syncthreads();
    int woff = 0;
    for (int w = 0; w < wid; ++w) woff += ws_[w];
    int run = boffs[blockIdx.x] + woff + incl - tsum;
#pragma unroll
    for (int j = 0; j < 4; ++j) {
        if (i0 + j < N) { offs[i0 + j] = run; cursor[i0 + j] = run; }
        run += v[j];
    }
    if (blockIdx.x == 0 && tid == 0) offs[N] = E;
}

// ---------- K4: per-edge ex = exp(leaky_relu(logit)), scatter to CSR slot --
// Segment-max subtraction skipped: logits bounded far below exp overflow for
// this model's scales; alpha = ex/denom identical up to rounding.
__global__ __launch_bounds__(256) void edge_logits_scatter(
    const float* __restrict__ ef,
    const int* __restrict__ src, const int* __restrict__ dst,
    const float* __restrict__ gbuf,   // g1|g2|c
    const float* __restrict__ pbuf, const float* __restrict__ qbuf,
    int* __restrict__ cursor, int2* __restrict__ spack, int E)
{
    int tid = threadIdx.x;
    int lane = tid & 15;
    int e = blockIdx.x * 16 + (tid >> 4);
    if (e >= E) return;
    const float* efr = ef + (size_t)e * D;
    float acc = 0.f;
#pragma unroll
    for (int p = 0; p < 2; ++p) {
        int idx = lane * 4 + p * 64;
        float4 a4  = *(const float4*)&efr[idx];
        float4 g14 = *(const float4*)&gbuf[idx];
        acc += a4.x * g14.x + a4.y * g14.y + a4.z * g14.z + a4.w * g14.w;
    }
#pragma unroll
    for (int off = 8; off >= 1; off >>= 1) acc += __shfl_xor(acc, off);
    if (lane == 0) {
        int s = src[e], d = dst[e];
        float a = acc + pbuf[s] + qbuf[d] + gbuf[256];
        float ev = a > 0.f ? a : 0.01f * a;
        int pos = atomicAdd(&cursor[d], 1);
        spack[pos] = make_int2(s, __float_as_int(__expf(ev)));
    }
}

// ---------- K5: gather, 2 nodes/wave (32 lanes x 8B), softmax-weighted -----
__global__ __launch_bounds__(256) void node_gather(
    const unsigned short* __restrict__ zb, const int2* __restrict__ spack,
    const int* __restrict__ offs, float* __restrict__ out, int N)
{
    int tid = threadIdx.x, half = tid & 31;
    int node = blockIdx.x * 8 + (tid >> 5);
    if (node >= N) return;
    int o0 = offs[node], o1 = offs[node + 1];
    float4 acc = make_float4(0.f, 0.f, 0.f, 0.f);
    float denom = 0.f;
    int j = o0;
    for (; j + 1 < o1; j += 2) {
        int2 p0 = spack[j], p1 = spack[j + 1];
        uint2 u0 = *(const uint2*)&zb[(size_t)p0.x * D + half * 4];
        uint2 u1 = *(const uint2*)&zb[(size_t)p1.x * D + half * 4];
        float x0 = __int_as_float(p0.y), x1 = __int_as_float(p1.y);
        denom += x0 + x1;
        acc.x += x0 * bf_lo(u0.x) + x1 * bf_lo(u1.x);
        acc.y += x0 * bf_hi(u0.x) + x1 * bf_hi(u1.x);
        acc.z += x0 * bf_lo(u0.y) + x1 * bf_lo(u1.y);
        acc.w += x0 * bf_hi(u0.y) + x1 * bf_hi(u1.y);
    }
    if (j < o1) {
        int2 p0 = spack[j];
        uint2 u0 = *(const uint2*)&zb[(size_t)p0.x * D + half * 4];
        float x0 = __int_as_float(p0.y);
        denom += x0;
        acc.x += x0 * bf_lo(u0.x);
        acc.y += x0 * bf_hi(u0.x);
        acc.z += x0 * bf_lo(u0.y);
        acc.w += x0 * bf_hi(u0.y);
    }
    if (o1 > o0) {
        float inv = 1.f / denom;
        acc.x *= inv; acc.y *= inv; acc.z *= inv; acc.w *= inv;
    }
    *(float4*)&out[(size_t)node * D + half * 4] = acc;
}

extern "C" void kernel_launch(void* const* d_in, const int* in_sizes, int n_in,
                              void* d_out, int out_size, void* d_ws, size_t ws_size,
                              hipStream_t stream) {
    const float* x     = (const float*)d_in[0];
    const float* ef    = (const float*)d_in[1];
    const int*   src   = (const int*)d_in[2];
    const int*   dst   = (const int*)d_in[3];
    const float* Wfc   = (const float*)d_in[4];
    const float* Wrel  = (const float*)d_in[5];
    const float* brel  = (const float*)d_in[6];
    const float* Wattn = (const float*)d_in[7];
    int N = in_sizes[0] / D;
    int E = in_sizes[2];
    int nb = (N + 1023) / 1024;
    float* out = (float*)d_out;

    // workspace layout (zb bf16 first; spack 8B-aligned; gbuf 16B-aligned)
    unsigned short* zb = (unsigned short*)d_ws;          // N*D bf16
    int2*  spack  = (int2*)(zb + (size_t)N * D);         // E
    float* pbuf   = (float*)(spack + E);                 // N
    float* qbuf   = pbuf + N;                            // N
    int*   cnt    = (int*)(qbuf + N);                    // N
    int*   cursor = cnt + N;                             // N
    int*   offs   = cursor + N;                          // N+16 (padded)
    int*   bsum   = offs + N + 16;                       // 256
    int*   boffs  = bsum + 256;                          // 256
    float* gbuf   = (float*)(boffs + 256);               // 257

    hipMemsetAsync(cnt, 0, (size_t)N * sizeof(int), stream);

    g_and_count<<<1 + (E + 255) / 256, 256, 0, stream>>>(Wrel, brel, Wattn, dst,
                                                         gbuf, cnt, E);
    zgemm_pq<<<(N + 63) / 64, 256, 0, stream>>>(x, Wfc, Wattn, gbuf, zb, pbuf,
                                                qbuf, N);
    partial_sums<<<nb, 256, 0, stream>>>(cnt, bsum, N);
    scan_partials<<<1, 256, 0, stream>>>(bsum, boffs, nb);
    local_scan<<<nb, 256, 0, stream>>>(cnt, boffs, offs, cursor, N, E);
    edge_logits_scatter<<<(E + 15) / 16, 256, 0, stream>>>(ef, src, dst, gbuf,
                                                           pbuf, qbuf, cursor,
                                                           spack, E);
    node_gather<<<(N + 7) / 8, 256, 0, stream>>>(zb, spack, offs, out, N);
}